// Round 1
// baseline (98.610 us; speedup 1.0000x reference)
//
#include <hip/hip_runtime.h>

#define MT 64   // number of event types M
#define KK 4    // number of kernels K

// ---------- helpers ----------
__device__ __forceinline__ float wredf(float v) {
  #pragma unroll
  for (int off = 32; off > 0; off >>= 1) v += __shfl_xor(v, off, 64);
  return v;
}
__device__ __forceinline__ double wredd(double v) {
  #pragma unroll
  for (int off = 32; off > 0; off >>= 1) v += __shfl_xor(v, off, 64);
  return v;
}
// T arrives as a 1-element array; reference does jnp.float32(T). Handle both
// int32 and float32 encodings robustly (deterministic given fixed input).
__device__ __forceinline__ float parse_T(const int* Tp) {
  int v = *Tp;
  if (v >= 1 && v <= 1000000000) return (float)v;   // plausible int
  return __int_as_float(v);                          // else it was float bits
}

// ---------- Phase 1: block-local decayed state P_b, block decay factor, compensator ----------
// One wave per event-block. lane = m' (source type), registers c0..c3 = k states.
// P_b[m',k] = sum_{j in block} exp(-gamma_k*(t_last(b)-t_j)) * 1{m_j=m'}
__global__ __launch_bounds__(512) void k_phase1(
    const float* __restrict__ t, const int* __restrict__ mi,
    const float* __restrict__ alpha, const float* __restrict__ gamma,
    const int* __restrict__ Tp,
    float* __restrict__ P, float* __restrict__ decf, float* __restrict__ comppart,
    int N, int B, int NB)
{
  __shared__ float asum[KK*MT];
  const int tid = threadIdx.x;
  if (tid < KK*MT) {               // asum[k][m] = sum_p alpha[k][m][p]
    const float4* row = (const float4*)(alpha + tid*MT);
    float s = 0.f;
    #pragma unroll
    for (int j = 0; j < MT/4; ++j) { float4 v = row[j]; s += (v.x+v.y)+(v.z+v.w); }
    asum[tid] = s;
  }
  __syncthreads();

  const float g0=gamma[0], g1=gamma[1], g2=gamma[2], g3=gamma[3];
  const float T = parse_T(Tp);
  const int wv = tid >> 6, lane = tid & 63;
  int b = blockIdx.x*8 + wv;
  if (b >= NB) return;
  b = __builtin_amdgcn_readfirstlane(b);   // make block-derived indices wave-uniform
  const int s0 = b*B;
  const int e0 = min(N, s0+B);

  float c0=0.f, c1=0.f, c2=0.f, c3=0.f;
  float comp = 0.f;
  if (s0 < N) {
    float tprev = t[s0];
    for (int i = s0; i < e0; ++i) {
      float ti = t[i]; int m = mi[i];
      float dt = ti - tprev; tprev = ti;
      float d0 = __expf(-g0*dt), d1 = __expf(-g1*dt),
            d2 = __expf(-g2*dt), d3 = __expf(-g3*dt);
      float inc = (lane == m) ? 1.f : 0.f;
      c0 = fmaf(c0,d0,inc); c1 = fmaf(c1,d1,inc);
      c2 = fmaf(c2,d2,inc); c3 = fmaf(c3,d3,inc);
    }
    // compensator: each lane handles its own events (coalesced)
    for (int j = s0+lane; j < e0; j += 64) {
      float x = T - t[j]; int mj = mi[j];
      comp += asum[0*MT+mj]*(1.f-__expf(-g0*x))
            + asum[1*MT+mj]*(1.f-__expf(-g1*x))
            + asum[2*MT+mj]*(1.f-__expf(-g2*x))
            + asum[3*MT+mj]*(1.f-__expf(-g3*x));
    }
  }
  float* Pb = P + (size_t)b*(MT*KK);
  Pb[0*MT+lane]=c0; Pb[1*MT+lane]=c1; Pb[2*MT+lane]=c2; Pb[3*MT+lane]=c3;

  // decay factor over the whole block: ref(b-1)=t[s0-1] -> ref(b)=t[e0-1] (clamped)
  int last  = e0 - 1;            if (last  < 0)   last  = 0;
  int plast = s0 - 1;            if (plast < 0)   plast = 0;
  if (plast > N-1) plast = N-1;
  float dtb = t[last] - t[plast];
  if (lane < KK) {
    float gk = (lane==0)?g0:(lane==1)?g1:(lane==2)?g2:g3;
    decf[b*KK + lane] = __expf(-gk*dtb);
  }
  comp = wredf(comp);
  if (lane == 0) comppart[b] = comp;
}

// ---------- Phase 2a: sequential scan within each group of blocks ----------
// thread = state component (k = tid>>6, m' = tid&63). Writes exclusive carries.
__global__ __launch_bounds__(256) void k_scan_group(
    const float* __restrict__ P, const float* __restrict__ decf,
    float* __restrict__ Cl, float* __restrict__ Ag, int NB, int NG)
{
  const int tid = threadIdx.x;
  const int g = blockIdx.x;
  const int GB = NB / NG;
  const int k = tid >> 6;
  float c = 0.f;
  const int bend = (g+1)*GB;
  for (int b = g*GB; b < bend; ++b) {
    Cl[(size_t)b*256 + tid] = c;                 // carry INTO block b (group-local)
    c = fmaf(c, decf[b*4 + k], P[(size_t)b*256 + tid]);
  }
  Ag[(size_t)g*256 + tid] = c;                   // group aggregate, ref = group's last ref time
}

// ---------- Phase 2b: scan the NG group aggregates ----------
__global__ __launch_bounds__(256) void k_scan_top(
    const float* __restrict__ t, const float* __restrict__ gamma,
    const float* __restrict__ Ag, float* __restrict__ GP,
    int N, int B, int NB, int NG)
{
  const int tid = threadIdx.x;
  const int k = tid >> 6;
  const float gk = gamma[k];
  const int GB = NB / NG;
  float c = 0.f;
  float tprev = t[0];                            // gref(-1), carry is 0 so value irrelevant
  for (int g = 0; g < NG; ++g) {
    GP[(size_t)g*256 + tid] = c;                 // carry INTO group g, ref = gref(g-1)
    int last = min((g+1)*GB*B, N) - 1;
    float tg = t[last];
    c = fmaf(c, __expf(-gk*(tg - tprev)), Ag[(size_t)g*256 + tid]);
    tprev = tg;
  }
}

// ---------- Phase 3: per-event intensity with carried state ----------
__global__ __launch_bounds__(512) void k_phase3(
    const float* __restrict__ t, const int* __restrict__ mi,
    const float* __restrict__ alpha, const float* __restrict__ gamma,
    const float* __restrict__ mu,
    const float* __restrict__ Cl, const float* __restrict__ GP,
    float* __restrict__ nllpart, int N, int B, int NB, int GB)
{
  __shared__ float4 AT4[MT*MT];                  // 64 KB: AT4[n*64+m'] = {gamma_k*alpha[k][m'][n]}
  const int tid = threadIdx.x;
  const float g0=gamma[0], g1=gamma[1], g2=gamma[2], g3=gamma[3];
  for (int idx = tid; idx < MT*MT; idx += 512) { // coalesced reads, transposed LDS write
    float a0 = alpha[0*MT*MT + idx];
    float a1 = alpha[1*MT*MT + idx];
    float a2 = alpha[2*MT*MT + idx];
    float a3 = alpha[3*MT*MT + idx];
    int m = idx >> 6, n = idx & 63;
    AT4[(n<<6) + m] = make_float4(g0*a0, g1*a1, g2*a2, g3*a3);
  }
  __syncthreads();

  const int wv = tid >> 6, lane = tid & 63;
  int b = blockIdx.x*8 + wv;
  if (b >= NB) return;
  b = __builtin_amdgcn_readfirstlane(b);
  const int s0 = b*B;
  const int e0 = min(N, s0+B);
  float nll = 0.f;
  if (s0 < N) {
    const int g = b / GB;
    const int plast = max(s0-1, 0);
    const int glast = max(g*GB*B - 1, 0);
    const float tp0 = t[plast];
    const float dfx = tp0 - t[glast];            // >= 0
    const float* Clb = Cl + (size_t)b*(MT*KK);
    const float* GPg = GP + (size_t)g*(MT*KK);
    // carry fixup: C_b = C_local + GP_g * exp(-gamma*(tref(b-1)-gref(g-1)))
    float c0 = fmaf(GPg[0*MT+lane], __expf(-g0*dfx), Clb[0*MT+lane]);
    float c1 = fmaf(GPg[1*MT+lane], __expf(-g1*dfx), Clb[1*MT+lane]);
    float c2 = fmaf(GPg[2*MT+lane], __expf(-g2*dfx), Clb[2*MT+lane]);
    float c3 = fmaf(GPg[3*MT+lane], __expf(-g3*dfx), Clb[3*MT+lane]);
    float tprev = tp0;
    float acc = 0.f;
    for (int i = s0; i < e0; ++i) {
      float ti = t[i]; int m = mi[i];
      float dt = ti - tprev; tprev = ti;
      c0 *= __expf(-g0*dt); c1 *= __expf(-g1*dt);
      c2 *= __expf(-g2*dt); c3 *= __expf(-g3*dt);      // h[i] (pre self-add)
      float4 a4 = AT4[(m<<6) + lane];                   // contiguous 16B/lane, conflict-free
      float p = a4.x*c0;
      p = fmaf(a4.y,c1,p); p = fmaf(a4.z,c2,p); p = fmaf(a4.w,c3,p);
      p = wredf(p);                                     // sum over m' (64 lanes)
      float lam = mu[m] + p;
      acc += __logf(lam);
      float inc = (lane == m) ? 1.f : 0.f;              // add self for future events
      c0 += inc; c1 += inc; c2 += inc; c3 += inc;
    }
    nll = acc;
  }
  if (lane == 0) nllpart[b] = nll;
}

// ---------- Final deterministic reduction ----------
__global__ __launch_bounds__(256) void k_final(
    const float* __restrict__ mu, const int* __restrict__ Tp,
    const float* __restrict__ comppart, const float* __restrict__ nllpart,
    float* __restrict__ out, int N, int NB)
{
  const int tid = threadIdx.x;
  double sc = 0.0, sn = 0.0;
  for (int b = tid; b < NB; b += 256) { sc += (double)comppart[b]; sn += (double)nllpart[b]; }
  double sm = (tid < MT) ? (double)mu[tid] : 0.0;
  sc = wredd(sc); sn = wredd(sn); sm = wredd(sm);
  __shared__ double s3[3][4];
  const int wv = tid >> 6, lane = tid & 63;
  if (lane == 0) { s3[0][wv]=sc; s3[1][wv]=sn; s3[2][wv]=sm; }
  __syncthreads();
  if (tid == 0) {
    double C = s3[0][0]+s3[0][1]+s3[0][2]+s3[0][3];
    double L = s3[1][0]+s3[1][1]+s3[1][2]+s3[1][3];
    double M = s3[2][0]+s3[2][1]+s3[2][2]+s3[2][3];
    double T = (double)parse_T(Tp);
    out[0] = (float)((C + T*M - L) / (double)N);
  }
}

extern "C" void kernel_launch(void* const* d_in, const int* in_sizes, int n_in,
                              void* d_out, int out_size, void* d_ws, size_t ws_size,
                              hipStream_t stream)
{
  const float* mu    = (const float*)d_in[0];
  const float* alpha = (const float*)d_in[1];   // (K, M, M)
  const float* gamma = (const float*)d_in[2];   // (K,)
  const float* t     = (const float*)d_in[3];   // (N,)
  const int*   mi    = (const int*)d_in[4];     // (N,) int32
  const int*   Tp    = (const int*)d_in[5];     // scalar
  const int N = in_sizes[3];
  const int NG = 16;
  int NB = 2048;                                 // event blocks (multiple of 128)
  while (NB > 128 && (size_t)(NB*518 + NG*512)*sizeof(float) > ws_size) NB >>= 1;
  const int B  = (N + NB - 1) / NB;
  const int GB = NB / NG;

  float* P   = (float*)d_ws;                     // NB*256
  float* Cl  = P   + (size_t)NB*256;             // NB*256
  float* dfc = Cl  + (size_t)NB*256;             // NB*4
  float* Ag  = dfc + (size_t)NB*4;               // NG*256
  float* GP  = Ag  + (size_t)NG*256;             // NG*256
  float* cpt = GP  + (size_t)NG*256;             // NB
  float* npt = cpt + NB;                         // NB

  const int wgs = NB / 8;                        // 8 waves (blocks) per 512-thread workgroup
  k_phase1    <<<wgs, 512, 0, stream>>>(t, mi, alpha, gamma, Tp, P, dfc, cpt, N, B, NB);
  k_scan_group<<<NG, 256, 0, stream>>>(P, dfc, Cl, Ag, NB, NG);
  k_scan_top  <<<1,   256, 0, stream>>>(t, gamma, Ag, GP, N, B, NB, NG);
  k_phase3    <<<wgs, 512, 0, stream>>>(t, mi, alpha, gamma, mu, Cl, GP, npt, N, B, NB, GB);
  k_final     <<<1,   256, 0, stream>>>(mu, Tp, cpt, npt, (float*)d_out, N, NB);
}

// Round 2
// 82.265 us; speedup vs baseline: 1.1987x; 1.1987x over previous
//
#include <hip/hip_runtime.h>

#define MT 64   // number of event types M
#define KK 4    // number of kernels K
#define NGRP 32 // scan groups

// ---------- helpers ----------
__device__ __forceinline__ float wredf(float v) {
  #pragma unroll
  for (int off = 32; off > 0; off >>= 1) v += __shfl_xor(v, off, 64);
  return v;
}
__device__ __forceinline__ double wredd(double v) {
  #pragma unroll
  for (int off = 32; off > 0; off >>= 1) v += __shfl_xor(v, off, 64);
  return v;
}
// T arrives as a 1-element array; reference does jnp.float32(T).
__device__ __forceinline__ float parse_T(const int* Tp) {
  int v = *Tp;
  if (v >= 1 && v <= 1000000000) return (float)v;
  return __int_as_float(v);
}

// ---------- asum[k*64+m] = sum_p alpha[k][m][p] ----------
__global__ __launch_bounds__(256) void k_asum(const float* __restrict__ alpha,
                                              float* __restrict__ asumW) {
  const int tid = threadIdx.x;  // 256 = K*M
  const float4* row = (const float4*)(alpha + tid * MT);
  float s = 0.f;
  #pragma unroll
  for (int j = 0; j < MT/4; ++j) { float4 v = row[j]; s += (v.x+v.y)+(v.z+v.w); }
  asumW[tid] = s;
}

// ---------- fully-parallel: decay factors d4[i] and compensator partials ----------
__global__ __launch_bounds__(256) void k_decay(
    const float* __restrict__ t, const int* __restrict__ mi,
    const float* __restrict__ gamma, const float* __restrict__ asumW,
    const int* __restrict__ Tp, float4* __restrict__ d4,
    float* __restrict__ cpt, int N)
{
  __shared__ float as[KK*MT];
  __shared__ float cw[4];
  const int tid = threadIdx.x;
  as[tid] = asumW[tid];
  __syncthreads();
  const float g0=gamma[0], g1=gamma[1], g2=gamma[2], g3=gamma[3];
  const float T = parse_T(Tp);
  const int i = blockIdx.x*256 + tid;
  float comp = 0.f;
  if (i < N) {
    float ti = t[i];
    float tp = (i > 0) ? t[i-1] : ti;
    float dt = ti - tp;
    if (d4) d4[i] = make_float4(__expf(-g0*dt), __expf(-g1*dt),
                                __expf(-g2*dt), __expf(-g3*dt));
    int m = mi[i];
    float x = T - ti;
    comp = as[0*MT+m]*(1.f-__expf(-g0*x)) + as[1*MT+m]*(1.f-__expf(-g1*x))
         + as[2*MT+m]*(1.f-__expf(-g2*x)) + as[3*MT+m]*(1.f-__expf(-g3*x));
  }
  comp = wredf(comp);
  if ((tid & 63) == 0) cw[tid>>6] = comp;
  __syncthreads();
  if (tid == 0) cpt[blockIdx.x] = cw[0]+cw[1]+cw[2]+cw[3];
}

// ---------- Phase 1: block-local q-space state, block decay factor ----------
// q_k[n] = sum_{j in block} exp(-gamma_k*(t_ref-t_j)) * gamma_k*alpha[k][m_j][n]
__global__ __launch_bounds__(512) void k_phase1(
    const float* __restrict__ t, const int* __restrict__ mi,
    const float* __restrict__ alpha, const float* __restrict__ gamma,
    const float4* __restrict__ d4,
    float* __restrict__ P, float* __restrict__ decf,
    int N, int B, int NB)
{
  __shared__ float4 AT4[MT*MT];            // AT4[m*64+n] = {gamma_k*alpha[k][m][n]}
  const int tid = threadIdx.x;
  const float g0=gamma[0], g1=gamma[1], g2=gamma[2], g3=gamma[3];
  for (int idx = tid; idx < MT*MT; idx += 512) {
    float a0 = alpha[0*MT*MT + idx], a1 = alpha[1*MT*MT + idx];
    float a2 = alpha[2*MT*MT + idx], a3 = alpha[3*MT*MT + idx];
    AT4[idx] = make_float4(g0*a0, g1*a1, g2*a2, g3*a3);
  }
  __syncthreads();

  const int wv = tid >> 6, lane = tid & 63;
  int b = blockIdx.x*8 + wv;
  if (b >= NB) return;
  b = __builtin_amdgcn_readfirstlane(b);
  const int s0 = b*B;
  const int e0 = min(N, s0+B);
  float q0=0.f, q1=0.f, q2=0.f, q3=0.f;
  if (s0 < N) {
    if (d4) {
      for (int i = s0; i < e0; ++i) {
        float4 d = d4[i];                  // uniform -> s_load_dwordx4
        int m = mi[i];
        float4 a = AT4[(m<<6) + lane];     // contiguous 16B/lane, conflict-free
        q0 = fmaf(q0, d.x, a.x); q1 = fmaf(q1, d.y, a.y);
        q2 = fmaf(q2, d.z, a.z); q3 = fmaf(q3, d.w, a.w);
      }
    } else {
      float tprev = t[s0];
      for (int i = s0; i < e0; ++i) {
        float ti = t[i]; int m = mi[i];
        float dt = ti - tprev; tprev = ti;
        float4 a = AT4[(m<<6) + lane];
        q0 = fmaf(q0, __expf(-g0*dt), a.x); q1 = fmaf(q1, __expf(-g1*dt), a.y);
        q2 = fmaf(q2, __expf(-g2*dt), a.z); q3 = fmaf(q3, __expf(-g3*dt), a.w);
      }
    }
  }
  float* Pb = P + (size_t)b*(MT*KK);
  Pb[0*MT+lane]=q0; Pb[1*MT+lane]=q1; Pb[2*MT+lane]=q2; Pb[3*MT+lane]=q3;

  int last  = max(e0-1, 0);
  int plast = min(max(s0-1, 0), N-1);
  float dtb = t[last] - t[plast];
  if (lane < KK) {
    float gk = (lane==0)?g0:(lane==1)?g1:(lane==2)?g2:g3;
    decf[b*KK + lane] = __expf(-gk*dtb);
  }
}

// ---------- Phase 2a: sequential scan within each group of blocks ----------
__global__ __launch_bounds__(256) void k_scan_group(
    const float* __restrict__ P, const float* __restrict__ decf,
    float* __restrict__ Cl, float* __restrict__ Ag, int NB, int NG)
{
  const int tid = threadIdx.x;
  const int g = blockIdx.x;
  const int GB = NB / NG;
  const int k = tid >> 6;
  float c = 0.f;
  const int bend = (g+1)*GB;
  for (int b = g*GB; b < bend; ++b) {
    Cl[(size_t)b*256 + tid] = c;
    c = fmaf(c, decf[b*4 + k], P[(size_t)b*256 + tid]);
  }
  Ag[(size_t)g*256 + tid] = c;
}

// ---------- Phase 2b: scan the NG group aggregates ----------
__global__ __launch_bounds__(256) void k_scan_top(
    const float* __restrict__ t, const float* __restrict__ gamma,
    const float* __restrict__ Ag, float* __restrict__ GP,
    int N, int B, int NB, int NG)
{
  const int tid = threadIdx.x;
  const int k = tid >> 6;
  const float gk = gamma[k];
  const int GB = NB / NG;
  float c = 0.f;
  float tprev = t[0];
  for (int g = 0; g < NG; ++g) {
    GP[(size_t)g*256 + tid] = c;
    int last = min((g+1)*GB*B, N) - 1;
    float tg = t[last];
    c = fmaf(c, __expf(-gk*(tg - tprev)), Ag[(size_t)g*256 + tid]);
    tprev = tg;
  }
}

// ---------- Phase 3: per-event intensity with carried q-state ----------
__global__ __launch_bounds__(512) void k_phase3(
    const float* __restrict__ t, const int* __restrict__ mi,
    const float* __restrict__ alpha, const float* __restrict__ gamma,
    const float* __restrict__ mu, const float4* __restrict__ d4,
    const float* __restrict__ Cl, const float* __restrict__ GP,
    float* __restrict__ npt, int N, int B, int NB, int GB)
{
  __shared__ float4 AT4[MT*MT];
  const int tid = threadIdx.x;
  const float g0=gamma[0], g1=gamma[1], g2=gamma[2], g3=gamma[3];
  for (int idx = tid; idx < MT*MT; idx += 512) {
    float a0 = alpha[0*MT*MT + idx], a1 = alpha[1*MT*MT + idx];
    float a2 = alpha[2*MT*MT + idx], a3 = alpha[3*MT*MT + idx];
    AT4[idx] = make_float4(g0*a0, g1*a1, g2*a2, g3*a3);
  }
  __syncthreads();

  const int wv = tid >> 6, lane = tid & 63;
  int b = blockIdx.x*8 + wv;
  if (b >= NB) return;
  b = __builtin_amdgcn_readfirstlane(b);
  const int s0 = b*B;
  const int e0 = min(N, s0+B);
  float nll = 0.f;
  if (s0 < N) {
    const int g = b / GB;
    const int plast = max(s0-1, 0);
    const int glast = max(g*GB*B - 1, 0);
    const float tp0 = t[plast];
    const float dfx = tp0 - t[glast];
    const float* Clb = Cl + (size_t)b*(MT*KK);
    const float* GPg = GP + (size_t)g*(MT*KK);
    float q0 = fmaf(GPg[0*MT+lane], __expf(-g0*dfx), Clb[0*MT+lane]);
    float q1 = fmaf(GPg[1*MT+lane], __expf(-g1*dfx), Clb[1*MT+lane]);
    float q2 = fmaf(GPg[2*MT+lane], __expf(-g2*dfx), Clb[2*MT+lane]);
    float q3 = fmaf(GPg[3*MT+lane], __expf(-g3*dfx), Clb[3*MT+lane]);
    const float mul = mu[lane];
    float acc = 0.f;                       // sum of log2(lam) on lane m_i
    if (d4) {
      for (int i = s0; i < e0; ++i) {
        float4 d = d4[i];                  // uniform -> s_load_dwordx4
        int m = mi[i];
        float s = q0*d.x; s = fmaf(q1,d.y,s); s = fmaf(q2,d.z,s); s = fmaf(q3,d.w,s);
        float lg = __log2f(s + mul);       // valid on every lane (all positive)
        acc += (lane == m) ? lg : 0.f;
        float4 a = AT4[(m<<6) + lane];
        q0 = fmaf(q0, d.x, a.x); q1 = fmaf(q1, d.y, a.y);
        q2 = fmaf(q2, d.z, a.z); q3 = fmaf(q3, d.w, a.w);
      }
    } else {
      float tprev = tp0;
      for (int i = s0; i < e0; ++i) {
        float ti = t[i]; int m = mi[i];
        float dt = ti - tprev; tprev = ti;
        float dx = __expf(-g0*dt), dy = __expf(-g1*dt),
              dz = __expf(-g2*dt), dw = __expf(-g3*dt);
        float s = q0*dx; s = fmaf(q1,dy,s); s = fmaf(q2,dz,s); s = fmaf(q3,dw,s);
        float lg = __log2f(s + mul);
        acc += (lane == m) ? lg : 0.f;
        float4 a = AT4[(m<<6) + lane];
        q0 = fmaf(q0, dx, a.x); q1 = fmaf(q1, dy, a.y);
        q2 = fmaf(q2, dz, a.z); q3 = fmaf(q3, dw, a.w);
      }
    }
    nll = wredf(acc);                      // once per block, not per event
  }
  if (lane == 0) npt[b] = nll;
}

// ---------- Final deterministic reduction ----------
__global__ __launch_bounds__(256) void k_final(
    const float* __restrict__ mu, const int* __restrict__ Tp,
    const float* __restrict__ cpt, int ncpt,
    const float* __restrict__ npt, int NB,
    float* __restrict__ out, int N)
{
  const int tid = threadIdx.x;
  double sc = 0.0, sn = 0.0;
  for (int b = tid; b < ncpt; b += 256) sc += (double)cpt[b];
  for (int b = tid; b < NB;   b += 256) sn += (double)npt[b];
  double sm = (tid < MT) ? (double)mu[tid] : 0.0;
  sc = wredd(sc); sn = wredd(sn); sm = wredd(sm);
  __shared__ double s3[3][4];
  const int wv = tid >> 6, lane = tid & 63;
  if (lane == 0) { s3[0][wv]=sc; s3[1][wv]=sn; s3[2][wv]=sm; }
  __syncthreads();
  if (tid == 0) {
    double C = s3[0][0]+s3[0][1]+s3[0][2]+s3[0][3];
    double L = (s3[1][0]+s3[1][1]+s3[1][2]+s3[1][3]) * 0.6931471805599453; // ln2
    double M = s3[2][0]+s3[2][1]+s3[2][2]+s3[2][3];
    double T = (double)parse_T(Tp);
    out[0] = (float)((C + T*M - L) / (double)N);
  }
}

extern "C" void kernel_launch(void* const* d_in, const int* in_sizes, int n_in,
                              void* d_out, int out_size, void* d_ws, size_t ws_size,
                              hipStream_t stream)
{
  const float* mu    = (const float*)d_in[0];
  const float* alpha = (const float*)d_in[1];   // (K, M, M)
  const float* gamma = (const float*)d_in[2];   // (K,)
  const float* t     = (const float*)d_in[3];   // (N,)
  const int*   mi    = (const int*)d_in[4];     // (N,) int32
  const int*   Tp    = (const int*)d_in[5];     // scalar
  const int N   = in_sizes[3];
  const int NDW = (N + 255) / 256;
  const int NG  = NGRP;

  // workspace sizing: asum(256) + [d4: N*4] + P(NB*256) + Cl(NB*256)
  //                   + decf(NB*4) + Ag/GP(2*NG*256) + cpt(NDW) + npt(NB)
  auto needF = [&](int nb, bool withd4) -> size_t {
    return 256 + (withd4 ? (size_t)N*4 : 0) + (size_t)nb*517 + 2*(size_t)NG*256 + NDW;
  };
  int NB = 4096; bool use_d4 = true;
  while (NB > 128 && needF(NB, true)*4 > ws_size) NB >>= 1;
  if (needF(NB, true)*4 > ws_size) {
    use_d4 = false;
    NB = 4096;
    while (NB > 128 && needF(NB, false)*4 > ws_size) NB >>= 1;
  }
  const int B  = (N + NB - 1) / NB;
  const int GB = NB / NG;

  float* asumW = (float*)d_ws;                        // 256
  float* d4f   = asumW + 256;                         // N*4 (if use_d4)
  float* P     = d4f + (use_d4 ? (size_t)N*4 : 0);    // NB*256
  float* Cl    = P   + (size_t)NB*256;                // NB*256
  float* dfc   = Cl  + (size_t)NB*256;                // NB*4
  float* Ag    = dfc + (size_t)NB*4;                  // NG*256
  float* GP    = Ag  + (size_t)NG*256;                // NG*256
  float* cpt   = GP  + (size_t)NG*256;                // NDW
  float* npt   = cpt + NDW;                           // NB
  float4* d4   = use_d4 ? (float4*)d4f : nullptr;

  const int wgs = NB / 8;
  k_asum      <<<1,   256, 0, stream>>>(alpha, asumW);
  k_decay     <<<NDW, 256, 0, stream>>>(t, mi, gamma, asumW, Tp, d4, cpt, N);
  k_phase1    <<<wgs, 512, 0, stream>>>(t, mi, alpha, gamma, d4, P, dfc, N, B, NB);
  k_scan_group<<<NG,  256, 0, stream>>>(P, dfc, Cl, Ag, NB, NG);
  k_scan_top  <<<1,   256, 0, stream>>>(t, gamma, Ag, GP, N, B, NB, NG);
  k_phase3    <<<wgs, 512, 0, stream>>>(t, mi, alpha, gamma, mu, d4, Cl, GP, npt, N, B, NB, GB);
  k_final     <<<1,   256, 0, stream>>>(mu, Tp, cpt, NDW, npt, NB, (float*)d_out, N);
}